// Round 16
// baseline (147.169 us; speedup 1.0000x reference)
//
#include <hip/hip_runtime.h>
#include <stdint.h>

typedef _Float16 f16;
typedef f16 f16x8 __attribute__((ext_vector_type(8)));
typedef float f32x4 __attribute__((ext_vector_type(4)));

#define NUM_NODES 20000
#define NUM_EDGES 65536
#define WIDTH 64
#define EDGE_FEAT 6
#define HIDDEN 128
#define BM 128            // edges per workgroup (grid 512, 2 async blocks/CU)
#define PADCH 132         // 128 h-chunks + bias + 3 zero pads (group prefetch)

#define XH_HALFS (NUM_NODES * WIDTH)   // 1,280,000 halfs for x in f16
#define XCONV_BLKS 625                 // 625 * 2048 halfs = 1,280,000 exactly
#define OUT_FLOATS (NUM_NODES * WIDTH) // 1,280,000
#define ZBLKS 313                      // 313 * 4096 >= OUT_FLOATS

// direct global->LDS DMA, 16B per lane. lds dest wave-uniform; HW adds lane*16.
__device__ __forceinline__ void gload_lds16(const f16* g, f16* l) {
  __builtin_amdgcn_global_load_lds(
      (const __attribute__((address_space(1))) unsigned int*)g,
      (__attribute__((address_space(3))) unsigned int*)l, 16, 0, 0);
}

// ---------------------------------------------------------------------------
// Prep: (a) W2g: 132 chunks of [64n x 64k] f16, transposed + XOR-granule
//       swizzled (chunk 128 = bias b2, 129..131 zeros); (b) x fp32->f16;
//       (c) zero `out`.
// ---------------------------------------------------------------------------
__global__ __launch_bounds__(256) void prep_kernel(
    const float* __restrict__ x, const float* __restrict__ W2,
    const float* __restrict__ b2, f16* __restrict__ ws_h,
    float* __restrict__ out)
{
  f16* x_h = ws_h;
  f16* W2g = ws_h + XH_HALFS;
  const int blk = blockIdx.x, tid = threadIdx.x;

  if (blk < PADCH) {
    const int ki = blk;
    if (ki > HIDDEN) {  // zero pad chunks 129..131
      f16x8 z;
      #pragma unroll
      for (int u = 0; u < 8; ++u) z[u] = (f16)0.f;
      *(f16x8*)&W2g[(size_t)ki * 4096 + tid * 16] = z;
      *(f16x8*)&W2g[(size_t)ki * 4096 + tid * 16 + 8] = z;
      return;
    }
    __shared__ float row[4096];
    const float* srcrow;
    if (ki < HIDDEN) {
      const float4* src = (const float4*)(W2 + (size_t)ki * 4096);
      #pragma unroll
      for (int i = 0; i < 4; ++i) {
        float4 v = src[tid + 256 * i];
        *(float4*)&row[(tid + 256 * i) * 4] = v;
      }
      __syncthreads();
      srcrow = row;
    } else {
      srcrow = b2;  // bias chunk
    }
    const int obase = tid * 16;
    f16x8 outv0, outv1;
    #pragma unroll
    for (int u = 0; u < 8; ++u) {
      int o = obase + u;
      int n = o >> 6, pg = (o >> 3) & 7, j = o & 7;
      int k = (pg ^ (n & 7)) * 8 + j;
      outv0[u] = (f16)srcrow[k * 64 + n];
    }
    #pragma unroll
    for (int u = 0; u < 8; ++u) {
      int o = obase + 8 + u;
      int n = o >> 6, pg = (o >> 3) & 7, j = o & 7;
      int k = (pg ^ (n & 7)) * 8 + j;
      outv1[u] = (f16)srcrow[k * 64 + n];
    }
    *(f16x8*)&W2g[(size_t)ki * 4096 + obase] = outv0;
    *(f16x8*)&W2g[(size_t)ki * 4096 + obase + 8] = outv1;
  } else if (blk < PADCH + XCONV_BLKS) {
    int idx = (blk - PADCH) * 2048 + tid * 8;
    if (idx + 8 <= XH_HALFS) {
      float4 a = *(const float4*)(x + idx);
      float4 b = *(const float4*)(x + idx + 4);
      f16x8 hv;
      hv[0] = (f16)a.x; hv[1] = (f16)a.y; hv[2] = (f16)a.z; hv[3] = (f16)a.w;
      hv[4] = (f16)b.x; hv[5] = (f16)b.y; hv[6] = (f16)b.z; hv[7] = (f16)b.w;
      *(f16x8*)&x_h[idx] = hv;
    }
  } else {
    int base = (blk - PADCH - XCONV_BLKS) * 4096 + tid * 16;
    float4 z = {0.f, 0.f, 0.f, 0.f};
    #pragma unroll
    for (int i = 0; i < 4; ++i) {
      int idx = base + i * 4;
      if (idx + 4 <= OUT_FLOATS) *(float4*)(out + idx) = z;
    }
  }
}

// ---------------------------------------------------------------------------
// Main kernel: grid 512, 256 thr (4 waves), 2 ASYNC blocks/CU, full K.
// Wave (mhalf,nhalf) = 64 edges x 32 cols; 16 MFMA per chunk.
// r16 = r15 + SA SOFTWARE PIPELINE: sa = xf*hv depends only on STATIC data
// (hbuf, xf) -> legally computed one chunk ahead into ping-pong regs
// (saP/saQ), with both chunks' bf reads batched at group top. The per-chunk
// critical chain collapses to ds_read -> MFMA; pk_mul + hv reads become
// filler under MFMA/ds latency. 2-chunk groups, 2-slot ring, vmcnt(0)
// group-top wait (DMA is 1 group old). LDS 64 KB -> 2 blocks/CU.
// ---------------------------------------------------------------------------
__global__ __launch_bounds__(256, 2) void nnconv_kernel(
    const float* __restrict__ ea, const float* __restrict__ W1,
    const float* __restrict__ b1, const int* __restrict__ senders,
    const int* __restrict__ receivers, const f16* __restrict__ ws_h,
    float* __restrict__ out)
{
  const f16* x_h = ws_h;
  const f16* W2g = ws_h + XH_HALFS;
  __shared__ __align__(16) f16 hbuf[HIDDEN * 128];  // 32,768 B
  __shared__ __align__(16) f16 ring[2 * 8192];      // 32,768 B (65,536 total)

  const int tid = threadIdx.x;
  const int lane = tid & 63, wid = tid >> 6;
  const int quad = lane >> 4, l15 = lane & 15;
  const int mhalf = wid >> 1, nhalf = wid & 1;
  const int e0 = blockIdx.x * BM;
  const int mbase = mhalf * 64;

  // ---- stage group 0 (chunks 0,1 = 8192 halfs) -> slot 0, FIRST
  const f16* wsl = W2g + wid * 2048 + (lane << 3);  // wave's group slice
  #pragma unroll
  for (int i = 0; i < 4; ++i)
    gload_lds16(wsl + i * 512, &ring[wid * 2048 + i * 512]);

  // ---- ea rows -> eaf (aliases ring slot 1; dead before group 1 staged)
  float* eaf = (float*)&ring[8192];    // 768 f32 = 3072 B
  if (tid < 192)
    ((float4*)eaf)[tid] = ((const float4*)(ea + (size_t)e0 * EDGE_FEAT))[tid];

  // ---- x fragments gathered DIRECTLY into registers (one-time)
  f16x8 xf[4][2];
  {
    int srows[4];
    #pragma unroll
    for (int t = 0; t < 4; ++t)
      srows[t] = senders[e0 + mbase + t * 16 + l15];
    #pragma unroll
    for (int t = 0; t < 4; ++t)
      #pragma unroll
      for (int kc = 0; kc < 2; ++kc)
        xf[t][kc] = *(const f16x8*)(x_h + (size_t)srows[t] * WIDTH +
                                    kc * 32 + quad * 8);
  }

  __syncthreads();  // eaf visible to all

  // ---- h precompute: thread (k = tid>>1, half) does 64 edges of row k
  {
    const int k = tid >> 1, half = tid & 1;
    float b1c = b1[k];
    float w1c[6];
    #pragma unroll
    for (int f = 0; f < 6; ++f) w1c[f] = W1[f * HIDDEN + k];
    f16* hrow = &hbuf[k * 128 + half * 64];
    const float* er = eaf + half * 64 * EDGE_FEAT;
    #pragma unroll 2
    for (int g8 = 0; g8 < 8; ++g8) {
      f16x8 hv;
      #pragma unroll
      for (int j = 0; j < 8; ++j) {
        const float* p = er + (g8 * 8 + j) * EDGE_FEAT;
        float s = b1c;
        #pragma unroll
        for (int f = 0; f < 6; ++f) s = fmaf(p[f], w1c[f], s);
        hv[j] = (f16)fmaxf(s, 0.f);
      }
      *(f16x8*)&hrow[g8 * 8] = hv;
    }
  }

  // ---- per-lane B-fragment offsets within a 4096-half chunk (swizzled)
  int boff[2][2];
  #pragma unroll
  for (int kc = 0; kc < 2; ++kc)
    #pragma unroll
    for (int nt = 0; nt < 2; ++nt) {
      int n = nhalf * 32 + nt * 16 + l15;
      int g = kc * 4 + quad;
      boff[kc][nt] = n * 64 + (g ^ (n & 7)) * 8;
    }

  const f16* hb = &hbuf[mbase + l15];  // hv[t] = hb[k*128 + t*16]

  f32x4 acc[4][2];
  #pragma unroll
  for (int t = 0; t < 4; ++t)
    #pragma unroll
    for (int nt = 0; nt < 2; ++nt)
      acc[t][nt] = (f32x4){0.f, 0.f, 0.f, 0.f};

  __syncthreads();  // hbuf ready; eaf dead -> slot 1 reusable

  // sa ping-pong registers: sa[2t+kc] = xf[t][kc] * h(chunk)[t]
  f16x8 saP[8], saQ[8];

#define MKSA(DST, HK)                                                         \
  {                                                                           \
    f16 hv_[4];                                                               \
    _Pragma("unroll") for (int t = 0; t < 4; ++t)                             \
      hv_[t] = hb[(HK) * 128 + t * 16];                                       \
    _Pragma("unroll") for (int t = 0; t < 4; ++t) {                           \
      DST[2 * t] = xf[t][0] * hv_[t];                                         \
      DST[2 * t + 1] = xf[t][1] * hv_[t];                                     \
    }                                                                         \
  }

#define RDBF(DST, CB)                                                         \
  _Pragma("unroll") for (int kc = 0; kc < 2; ++kc)                            \
    _Pragma("unroll") for (int nt = 0; nt < 2; ++nt)                          \
      DST[kc][nt] = *(const f16x8*)&(CB)[boff[kc][nt]];

#define MMSA(SA, BF)                                                          \
  __builtin_amdgcn_s_setprio(1);                                              \
  _Pragma("unroll") for (int t = 0; t < 4; ++t)                               \
    _Pragma("unroll") for (int nt = 0; nt < 2; ++nt)                          \
      acc[t][nt] = __builtin_amdgcn_mfma_f32_16x16x32_f16(                    \
          SA[2 * t], BF[0][nt], acc[t][nt], 0, 0, 0);                         \
  _Pragma("unroll") for (int t = 0; t < 4; ++t)                               \
    _Pragma("unroll") for (int nt = 0; nt < 2; ++nt)                          \
      acc[t][nt] = __builtin_amdgcn_mfma_f32_16x16x32_f16(                    \
          SA[2 * t + 1], BF[1][nt], acc[t][nt], 0, 0, 0);                     \
  __builtin_amdgcn_s_setprio(0);

  // one group: wait (DMA 1 group old) + barrier; stage G+1; batch BOTH
  // chunks' bf reads; MFMA c0 while sa(c1-next) pk_muls fill ds latency.
#define GSTEP(G, SL, SD)                                                      \
  {                                                                           \
    asm volatile("s_waitcnt vmcnt(0) lgkmcnt(0)\n\ts_barrier" ::: "memory");  \
    __builtin_amdgcn_sched_barrier(0);                                        \
    {                                                                         \
      const f16* s_ = wsl + (size_t)((G) + 1) * 8192;                         \
      f16* d_ = &ring[(SD) * 8192 + wid * 2048];                              \
      _Pragma("unroll") for (int i_ = 0; i_ < 4; ++i_)                        \
        gload_lds16(s_ + i_ * 512, d_ + i_ * 512);                            \
    }                                                                         \
    __builtin_amdgcn_sched_barrier(0);                                        \
    const f16* gb_ = &ring[(SL) * 8192];                                      \
    f16x8 bfP_[2][2], bfQ_[2][2];                                             \
    RDBF(bfP_, gb_);                                                          \
    RDBF(bfQ_, gb_ + 4096);                                                   \
    {                                                                         \
      const int nk_ = (2 * (G) + 1 < 128) ? 2 * (G) + 1 : 127;                \
      MKSA(saQ, nk_);                                                         \
    }                                                                         \
    MMSA(saP, bfP_);                                                          \
    {                                                                         \
      const int nk_ = (2 * (G) + 2 < 128) ? 2 * (G) + 2 : 127;                \
      MKSA(saP, nk_);                                                         \
    }                                                                         \
    MMSA(saQ, bfQ_);                                                          \
  }

  // ---- prologue: sa for chunk 0
  MKSA(saP, 0);

  // ---- main loop: 64 groups (chunks 0..127); g=63 stages chunks 128,129
  #pragma unroll 1
  for (int g = 0; g < 64; g += 2) {
    GSTEP(g,     0, 1);
    GSTEP(g + 1, 1, 0);
  }
#undef GSTEP

  // ---- tail: chunk 128 (bias row, h == 1) from slot 0 (uses xf directly)
  asm volatile("s_waitcnt vmcnt(0) lgkmcnt(0)\n\ts_barrier" ::: "memory");
  __builtin_amdgcn_sched_barrier(0);
  {
    f16x8 bf_[2][2];
    RDBF(bf_, &ring[0]);
    __builtin_amdgcn_s_setprio(1);
    #pragma unroll
    for (int t = 0; t < 4; ++t)
      #pragma unroll
      for (int nt = 0; nt < 2; ++nt) {
        acc[t][nt] = __builtin_amdgcn_mfma_f32_16x16x32_f16(
            xf[t][0], bf_[0][nt], acc[t][nt], 0, 0, 0);
        acc[t][nt] = __builtin_amdgcn_mfma_f32_16x16x32_f16(
            xf[t][1], bf_[1][nt], acc[t][nt], 0, 0, 0);
      }
    __builtin_amdgcn_s_setprio(0);
  }
#undef MMSA
#undef RDBF
#undef MKSA

  // ---- epilogue: C row = quad*4 + reg, col = l15; scatter-add (full sums)
  #pragma unroll
  for (int t = 0; t < 4; ++t) {
    int ebase = e0 + mbase + t * 16 + quad * 4;
    int rc[4];
    #pragma unroll
    for (int r = 0; r < 4; ++r) rc[r] = receivers[ebase + r];
    #pragma unroll
    for (int nt = 0; nt < 2; ++nt) {
      int v = (nhalf * 2 + nt) * 16 + l15;
      #pragma unroll
      for (int r = 0; r < 4; ++r)
        atomicAdd(out + (size_t)rc[r] * WIDTH + v, acc[t][nt][r]);
    }
  }
}

extern "C" void kernel_launch(void* const* d_in, const int* in_sizes, int n_in,
                              void* d_out, int out_size, void* d_ws, size_t ws_size,
                              hipStream_t stream) {
  const float* x  = (const float*)d_in[0];
  const float* ea = (const float*)d_in[1];
  const float* W1 = (const float*)d_in[2];
  const float* b1 = (const float*)d_in[3];
  const float* W2 = (const float*)d_in[4];
  const float* b2 = (const float*)d_in[5];
  const int* snd  = (const int*)d_in[6];
  const int* rcv  = (const int*)d_in[7];
  float* out = (float*)d_out;
  f16* wsh = (f16*)d_ws;

  const int prep_grid = PADCH + XCONV_BLKS + ZBLKS;
  prep_kernel<<<prep_grid, 256, 0, stream>>>(x, W2, b2, wsh, out);
  nnconv_kernel<<<NUM_EDGES / BM, 256, 0, stream>>>(ea, W1, b1, snd, rcv, wsh, out);
}

// Round 17
// 145.532 us; speedup vs baseline: 1.0112x; 1.0112x over previous
//
#include <hip/hip_runtime.h>
#include <stdint.h>

typedef _Float16 f16;
typedef f16 f16x8 __attribute__((ext_vector_type(8)));
typedef float f32x4 __attribute__((ext_vector_type(4)));

#define NUM_NODES 20000
#define NUM_EDGES 65536
#define WIDTH 64
#define EDGE_FEAT 6
#define HIDDEN 128
#define BM 128            // edges per workgroup (grid 512, 2 async blocks/CU)
#define PADCH 132         // 128 h-chunks + bias + 3 zero pads (group prefetch)

#define XH_HALFS (NUM_NODES * WIDTH)   // 1,280,000 halfs for x in f16
#define XCONV_BLKS 625                 // 625 * 2048 halfs = 1,280,000 exactly
#define OUT_FLOATS (NUM_NODES * WIDTH) // 1,280,000
#define ZBLKS 313                      // 313 * 4096 >= OUT_FLOATS

// direct global->LDS DMA, 16B per lane. lds dest wave-uniform; HW adds lane*16.
__device__ __forceinline__ void gload_lds16(const f16* g, f16* l) {
  __builtin_amdgcn_global_load_lds(
      (const __attribute__((address_space(1))) unsigned int*)g,
      (__attribute__((address_space(3))) unsigned int*)l, 16, 0, 0);
}

// ---------------------------------------------------------------------------
// Prep: (a) W2g: 132 chunks of [64n x 64k] f16, transposed + XOR-granule
//       swizzled (chunk 128 = bias b2, 129..131 zeros); (b) x fp32->f16;
//       (c) zero `out`.
// ---------------------------------------------------------------------------
__global__ __launch_bounds__(256) void prep_kernel(
    const float* __restrict__ x, const float* __restrict__ W2,
    const float* __restrict__ b2, f16* __restrict__ ws_h,
    float* __restrict__ out)
{
  f16* x_h = ws_h;
  f16* W2g = ws_h + XH_HALFS;
  const int blk = blockIdx.x, tid = threadIdx.x;

  if (blk < PADCH) {
    const int ki = blk;
    if (ki > HIDDEN) {  // zero pad chunks 129..131
      f16x8 z;
      #pragma unroll
      for (int u = 0; u < 8; ++u) z[u] = (f16)0.f;
      *(f16x8*)&W2g[(size_t)ki * 4096 + tid * 16] = z;
      *(f16x8*)&W2g[(size_t)ki * 4096 + tid * 16 + 8] = z;
      return;
    }
    __shared__ float row[4096];
    const float* srcrow;
    if (ki < HIDDEN) {
      const float4* src = (const float4*)(W2 + (size_t)ki * 4096);
      #pragma unroll
      for (int i = 0; i < 4; ++i) {
        float4 v = src[tid + 256 * i];
        *(float4*)&row[(tid + 256 * i) * 4] = v;
      }
      __syncthreads();
      srcrow = row;
    } else {
      srcrow = b2;  // bias chunk
    }
    const int obase = tid * 16;
    f16x8 outv0, outv1;
    #pragma unroll
    for (int u = 0; u < 8; ++u) {
      int o = obase + u;
      int n = o >> 6, pg = (o >> 3) & 7, j = o & 7;
      int k = (pg ^ (n & 7)) * 8 + j;
      outv0[u] = (f16)srcrow[k * 64 + n];
    }
    #pragma unroll
    for (int u = 0; u < 8; ++u) {
      int o = obase + 8 + u;
      int n = o >> 6, pg = (o >> 3) & 7, j = o & 7;
      int k = (pg ^ (n & 7)) * 8 + j;
      outv1[u] = (f16)srcrow[k * 64 + n];
    }
    *(f16x8*)&W2g[(size_t)ki * 4096 + obase] = outv0;
    *(f16x8*)&W2g[(size_t)ki * 4096 + obase + 8] = outv1;
  } else if (blk < PADCH + XCONV_BLKS) {
    int idx = (blk - PADCH) * 2048 + tid * 8;
    if (idx + 8 <= XH_HALFS) {
      float4 a = *(const float4*)(x + idx);
      float4 b = *(const float4*)(x + idx + 4);
      f16x8 hv;
      hv[0] = (f16)a.x; hv[1] = (f16)a.y; hv[2] = (f16)a.z; hv[3] = (f16)a.w;
      hv[4] = (f16)b.x; hv[5] = (f16)b.y; hv[6] = (f16)b.z; hv[7] = (f16)b.w;
      *(f16x8*)&x_h[idx] = hv;
    }
  } else {
    int base = (blk - PADCH - XCONV_BLKS) * 4096 + tid * 16;
    float4 z = {0.f, 0.f, 0.f, 0.f};
    #pragma unroll
    for (int i = 0; i < 4; ++i) {
      int idx = base + i * 4;
      if (idx + 4 <= OUT_FLOATS) *(float4*)(out + idx) = z;
    }
  }
}

// ---------------------------------------------------------------------------
// Main kernel: grid 512, 256 thr (4 waves), 2 ASYNC blocks/CU, full K.
// Wave (mhalf,nhalf) = 64 edges x 32 cols; 16 MFMA per chunk.
// Session-best structure (r15): 2 chunks (16 KB group) per barrier, 2-group
// LDS ring. Within a group, chunk c1's ds_reads issue under chunk c0's
// MFMAs (no intervening barrier). x fragments gathered directly to
// registers (no xt). h precomputed to LDS (VALU-diet loop). 64 barriers
// total. LDS = hbuf 32 KB + ring 32 KB = 64 KB -> 2 blocks/CU.
// Measured: 77.1 us nnconv / 144.0 us total, MfmaUtil 37%.
// ---------------------------------------------------------------------------
__global__ __launch_bounds__(256, 2) void nnconv_kernel(
    const float* __restrict__ ea, const float* __restrict__ W1,
    const float* __restrict__ b1, const int* __restrict__ senders,
    const int* __restrict__ receivers, const f16* __restrict__ ws_h,
    float* __restrict__ out)
{
  const f16* x_h = ws_h;
  const f16* W2g = ws_h + XH_HALFS;
  __shared__ __align__(16) f16 hbuf[HIDDEN * 128];  // 32,768 B
  __shared__ __align__(16) f16 ring[2 * 8192];      // 32,768 B (65,536 total)

  const int tid = threadIdx.x;
  const int lane = tid & 63, wid = tid >> 6;
  const int quad = lane >> 4, l15 = lane & 15;
  const int mhalf = wid >> 1, nhalf = wid & 1;
  const int e0 = blockIdx.x * BM;
  const int mbase = mhalf * 64;

  // ---- stage group 0 (chunks 0,1 = 8192 halfs) -> slot 0, FIRST
  const f16* wsl = W2g + wid * 2048 + (lane << 3);  // wave's group slice
  #pragma unroll
  for (int i = 0; i < 4; ++i)
    gload_lds16(wsl + i * 512, &ring[wid * 2048 + i * 512]);

  // ---- ea rows -> eaf (aliases ring slot 1; dead before group 1 staged)
  float* eaf = (float*)&ring[8192];    // 768 f32 = 3072 B
  if (tid < 192)
    ((float4*)eaf)[tid] = ((const float4*)(ea + (size_t)e0 * EDGE_FEAT))[tid];

  // ---- x fragments gathered DIRECTLY into registers (one-time)
  f16x8 xf[4][2];
  {
    int srows[4];
    #pragma unroll
    for (int t = 0; t < 4; ++t)
      srows[t] = senders[e0 + mbase + t * 16 + l15];
    #pragma unroll
    for (int t = 0; t < 4; ++t)
      #pragma unroll
      for (int kc = 0; kc < 2; ++kc)
        xf[t][kc] = *(const f16x8*)(x_h + (size_t)srows[t] * WIDTH +
                                    kc * 32 + quad * 8);
  }

  __syncthreads();  // eaf visible to all

  // ---- h precompute: thread (k = tid>>1, half) does 64 edges of row k
  {
    const int k = tid >> 1, half = tid & 1;
    float b1c = b1[k];
    float w1c[6];
    #pragma unroll
    for (int f = 0; f < 6; ++f) w1c[f] = W1[f * HIDDEN + k];
    f16* hrow = &hbuf[k * 128 + half * 64];
    const float* er = eaf + half * 64 * EDGE_FEAT;
    #pragma unroll 2
    for (int g8 = 0; g8 < 8; ++g8) {
      f16x8 hv;
      #pragma unroll
      for (int j = 0; j < 8; ++j) {
        const float* p = er + (g8 * 8 + j) * EDGE_FEAT;
        float s = b1c;
        #pragma unroll
        for (int f = 0; f < 6; ++f) s = fmaf(p[f], w1c[f], s);
        hv[j] = (f16)fmaxf(s, 0.f);
      }
      *(f16x8*)&hrow[g8 * 8] = hv;
    }
  }

  // ---- per-lane B-fragment offsets within a 4096-half chunk (swizzled)
  int boff[2][2];
  #pragma unroll
  for (int kc = 0; kc < 2; ++kc)
    #pragma unroll
    for (int nt = 0; nt < 2; ++nt) {
      int n = nhalf * 32 + nt * 16 + l15;
      int g = kc * 4 + quad;
      boff[kc][nt] = n * 64 + (g ^ (n & 7)) * 8;
    }

  const f16* hb = &hbuf[mbase + l15];  // hv[t] = hb[k*128 + t*16]

  f32x4 acc[4][2];
  #pragma unroll
  for (int t = 0; t < 4; ++t)
    #pragma unroll
    for (int nt = 0; nt < 2; ++nt)
      acc[t][nt] = (f32x4){0.f, 0.f, 0.f, 0.f};

  __syncthreads();  // hbuf ready; eaf dead -> slot 1 reusable

  // one chunk's worth of compute from an LDS chunk base CB with h row HK
#define CHUNK(CB, HK)                                                         \
  {                                                                           \
    f16x8 bf_[2][2];                                                          \
    _Pragma("unroll") for (int kc = 0; kc < 2; ++kc)                          \
      _Pragma("unroll") for (int nt = 0; nt < 2; ++nt)                        \
        bf_[kc][nt] = *(const f16x8*)&(CB)[boff[kc][nt]];                     \
    f16 hv_[4];                                                               \
    _Pragma("unroll") for (int t = 0; t < 4; ++t)                             \
      hv_[t] = hb[(HK) * 128 + t * 16];                                       \
    f16x8 sa0_[4], sa1_[4];                                                   \
    _Pragma("unroll") for (int t = 0; t < 4; ++t) {                           \
      sa0_[t] = xf[t][0] * hv_[t];                                            \
      sa1_[t] = xf[t][1] * hv_[t];                                            \
    }                                                                         \
    __builtin_amdgcn_s_setprio(1);                                            \
    _Pragma("unroll") for (int t = 0; t < 4; ++t)                             \
      _Pragma("unroll") for (int nt = 0; nt < 2; ++nt)                        \
        acc[t][nt] = __builtin_amdgcn_mfma_f32_16x16x32_f16(                  \
            sa0_[t], bf_[0][nt], acc[t][nt], 0, 0, 0);                        \
    _Pragma("unroll") for (int t = 0; t < 4; ++t)                             \
      _Pragma("unroll") for (int nt = 0; nt < 2; ++nt)                        \
        acc[t][nt] = __builtin_amdgcn_mfma_f32_16x16x32_f16(                  \
            sa1_[t], bf_[1][nt], acc[t][nt], 0, 0, 0);                        \
    __builtin_amdgcn_s_setprio(0);                                            \
  }

  // one group: wait (DMA issued last group, ~1700 cyc old) + barrier;
  // stage group G+1 into SD; compute chunks 2G, 2G+1 from slot SL.
#define GSTEP(G, SL, SD)                                                      \
  {                                                                           \
    asm volatile("s_waitcnt vmcnt(0) lgkmcnt(0)\n\ts_barrier" ::: "memory");  \
    __builtin_amdgcn_sched_barrier(0);                                        \
    {                                                                         \
      const f16* s_ = wsl + (size_t)((G) + 1) * 8192;                         \
      f16* d_ = &ring[(SD) * 8192 + wid * 2048];                              \
      _Pragma("unroll") for (int i_ = 0; i_ < 4; ++i_)                        \
        gload_lds16(s_ + i_ * 512, d_ + i_ * 512);                            \
    }                                                                         \
    __builtin_amdgcn_sched_barrier(0);                                        \
    const f16* gb_ = &ring[(SL) * 8192];                                      \
    CHUNK(gb_, 2 * (G));                                                      \
    CHUNK(gb_ + 4096, 2 * (G) + 1);                                           \
  }

  // ---- main loop: 64 groups (chunks 0..127); g=63 stages chunks 128,129
  #pragma unroll 1
  for (int g = 0; g < 64; g += 2) {
    GSTEP(g,     0, 1);
    GSTEP(g + 1, 1, 0);
  }
#undef GSTEP

  // ---- tail: chunk 128 (bias row, h == 1) from slot 0
  asm volatile("s_waitcnt vmcnt(0) lgkmcnt(0)\n\ts_barrier" ::: "memory");
  __builtin_amdgcn_sched_barrier(0);
  {
    f16x8 bf_[2][2];
    #pragma unroll
    for (int kc = 0; kc < 2; ++kc)
      #pragma unroll
      for (int nt = 0; nt < 2; ++nt)
        bf_[kc][nt] = *(const f16x8*)&ring[boff[kc][nt]];
    __builtin_amdgcn_s_setprio(1);
    #pragma unroll
    for (int t = 0; t < 4; ++t)
      #pragma unroll
      for (int nt = 0; nt < 2; ++nt) {
        acc[t][nt] = __builtin_amdgcn_mfma_f32_16x16x32_f16(
            xf[t][0], bf_[0][nt], acc[t][nt], 0, 0, 0);
        acc[t][nt] = __builtin_amdgcn_mfma_f32_16x16x32_f16(
            xf[t][1], bf_[1][nt], acc[t][nt], 0, 0, 0);
      }
    __builtin_amdgcn_s_setprio(0);
  }
#undef CHUNK

  // ---- epilogue: C row = quad*4 + reg, col = l15; scatter-add (full sums)
  #pragma unroll
  for (int t = 0; t < 4; ++t) {
    int ebase = e0 + mbase + t * 16 + quad * 4;
    int rc[4];
    #pragma unroll
    for (int r = 0; r < 4; ++r) rc[r] = receivers[ebase + r];
    #pragma unroll
    for (int nt = 0; nt < 2; ++nt) {
      int v = (nhalf * 2 + nt) * 16 + l15;
      #pragma unroll
      for (int r = 0; r < 4; ++r)
        atomicAdd(out + (size_t)rc[r] * WIDTH + v, acc[t][nt][r]);
    }
  }
}

extern "C" void kernel_launch(void* const* d_in, const int* in_sizes, int n_in,
                              void* d_out, int out_size, void* d_ws, size_t ws_size,
                              hipStream_t stream) {
  const float* x  = (const float*)d_in[0];
  const float* ea = (const float*)d_in[1];
  const float* W1 = (const float*)d_in[2];
  const float* b1 = (const float*)d_in[3];
  const float* W2 = (const float*)d_in[4];
  const float* b2 = (const float*)d_in[5];
  const int* snd  = (const int*)d_in[6];
  const int* rcv  = (const int*)d_in[7];
  float* out = (float*)d_out;
  f16* wsh = (f16*)d_ws;

  const int prep_grid = PADCH + XCONV_BLKS + ZBLKS;
  prep_kernel<<<prep_grid, 256, 0, stream>>>(x, W2, b2, wsh, out);
  nnconv_kernel<<<NUM_EDGES / BM, 256, 0, stream>>>(ea, W1, b1, snd, rcv, wsh, out);
}